// Round 20
// baseline (687.710 us; speedup 1.0000x reference)
//
#include <hip/hip_runtime.h>
#include <hip/hip_bf16.h>

#define HS 12       // stride for xr rows (48B)
#define XLU 8       // stride (uints) for bf16 xl rows (32B)
#define USU 16      // stride (uints) for packed bf16 u-rows (64B = 1 line)
#define NPART 8     // p-histogram partitions
#define N_CAP 200000
#define M_CAP 32768
#define E_CAP 3200000
#define BKS 10
#define CHUNK 6144

// Static device scratch
__device__ __align__(32) unsigned g_xlbA[(size_t)N_CAP * XLU];
__device__ __align__(32) unsigned g_xlbB[(size_t)N_CAP * XLU];
__device__ __align__(16) float    g_xrA[(size_t)N_CAP * HS];
__device__ __align__(16) float    g_xrB[(size_t)N_CAP * HS];
__device__ __align__(64) unsigned g_us[(size_t)N_CAP * USU];
__device__ __align__(64) unsigned g_ud[(size_t)N_CAP * USU];
__device__ __align__(64) unsigned g_ut[(size_t)N_CAP * USU];
__device__ int      g_cnt[N_CAP];
__device__ int      g_off[N_CAP];
__device__ int      g_bcnt[256];
__device__ int      g_boff[256];
__device__ int      g_bcur[256];
__device__ unsigned g_staged[E_CAP];
__device__ int      g_csrc[E_CAP];
__device__ __align__(64) float g_pp[NPART][M_CAP];
__device__ float    g_p[M_CAP];
__device__ float    g_vsum[1];

__device__ __forceinline__ unsigned* xlb_buf(int s) { return s ? g_xlbB : g_xlbA; }
__device__ __forceinline__ float*    xr_buf(int s)  { return s ? g_xrB : g_xrA; }

__device__ __forceinline__ void load_row10(const float* row, float* v) {
    const float4* r4 = (const float4*)row;
    float4 a = r4[0], b = r4[1];
    float2 c = ((const float2*)row)[4];
    v[0] = a.x; v[1] = a.y; v[2] = a.z; v[3] = a.w;
    v[4] = b.x; v[5] = b.y; v[6] = b.z; v[7] = b.w;
    v[8] = c.x; v[9] = c.y;
}
__device__ __forceinline__ unsigned pack_bf2(float a, float b) {
    unsigned ua = __float_as_uint(a); ua = (ua + 0x7fffu + ((ua >> 16) & 1u)) >> 16;
    unsigned ub = __float_as_uint(b); ub = (ub + 0x7fffu + ((ub >> 16) & 1u)) >> 16;
    return ua | (ub << 16);
}
__device__ __forceinline__ void unpack_bf2(unsigned u, float& a, float& b) {
    a = __uint_as_float(u << 16);
    b = __uint_as_float(u & 0xffff0000u);
}
__device__ __forceinline__ void load_xlb(const unsigned* row, float* v) {
    uint4 q = ((const uint4*)row)[0];
    unsigned q4 = row[4];
    unpack_bf2(q.x, v[0], v[1]); unpack_bf2(q.y, v[2], v[3]);
    unpack_bf2(q.z, v[4], v[5]); unpack_bf2(q.w, v[6], v[7]);
    unpack_bf2(q4, v[8], v[9]);
}
__device__ __forceinline__ void store_xlb(unsigned* row, const float* v) {
    ((uint4*)row)[0] = make_uint4(pack_bf2(v[0], v[1]), pack_bf2(v[2], v[3]),
                                  pack_bf2(v[4], v[5]), pack_bf2(v[6], v[7]));
    row[4] = pack_bf2(v[8], v[9]);
}
__device__ __forceinline__ void load_row20_bf(const unsigned* row, float* v) {
    const uint4* r4 = (const uint4*)row;
    uint4 q0 = r4[0], q1 = r4[1], q2 = r4[2];
    unpack_bf2(q0.x, v[0], v[1]);   unpack_bf2(q0.y, v[2], v[3]);
    unpack_bf2(q0.z, v[4], v[5]);   unpack_bf2(q0.w, v[6], v[7]);
    unpack_bf2(q1.x, v[8], v[9]);   unpack_bf2(q1.y, v[10], v[11]);
    unpack_bf2(q1.z, v[12], v[13]); unpack_bf2(q1.w, v[14], v[15]);
    unpack_bf2(q2.x, v[16], v[17]); unpack_bf2(q2.y, v[18], v[19]);
}
__device__ __forceinline__ void store_row20_bf(unsigned* row, const float* v) {
    uint4* r4 = (uint4*)row;
    r4[0] = make_uint4(pack_bf2(v[0], v[1]), pack_bf2(v[2], v[3]),
                       pack_bf2(v[4], v[5]), pack_bf2(v[6], v[7]));
    r4[1] = make_uint4(pack_bf2(v[8], v[9]), pack_bf2(v[10], v[11]),
                       pack_bf2(v[12], v[13]), pack_bf2(v[14], v[15]));
    r4[2] = make_uint4(pack_bf2(v[16], v[17]), pack_bf2(v[18], v[19]), 0u, 0u);
    r4[3] = make_uint4(0u, 0u, 0u, 0u);
}

// ---- shared gather core: ALL 4 sublanes end with identical h[10] ----
__device__ __forceinline__ void gather_core(int n, int sub, const unsigned* xlb,
                                            const float* xr_arr, const float* satt,
                                            const float* sb, float* hout) {
    float xr[10];
    load_row10(&xr_arr[(size_t)n * HS], xr);
    float m = -1e30f, den = 0.f, num[10];
#pragma unroll
    for (int j = 0; j < 10; j++) num[j] = 0.f;
    if (sub == 0) {
        float xls[10];
        load_xlb(&xlb[(size_t)n * XLU], xls);
        float acc = 0.f;
#pragma unroll
        for (int k = 0; k < 10; k++) {
            float v = xls[k] + xr[k];
            v = (v > 0.f) ? v : 0.2f * v;
            acc += v * satt[k];
            num[k] = xls[k];
        }
        m = acc;
        den = 1.f;
    }
    int lo = g_off[n], hi = lo + g_cnt[n];
    for (int e = lo + sub; e < hi; e += 4) {
        int s = g_csrc[e];
        float xls[10];
        load_xlb(&xlb[(size_t)s * XLU], xls);
        float acc = 0.f;
#pragma unroll
        for (int k = 0; k < 10; k++) {
            float v = xls[k] + xr[k];
            v = (v > 0.f) ? v : 0.2f * v;
            acc += v * satt[k];
        }
        if (acc > m) {
            float sc = __expf(m - acc);
            den *= sc;
#pragma unroll
            for (int j = 0; j < 10; j++) num[j] *= sc;
            m = acc;
        }
        float w = __expf(acc - m);
        den += w;
#pragma unroll
        for (int j = 0; j < 10; j++) num[j] += w * xls[j];
    }
#pragma unroll
    for (int off = 1; off <= 2; off <<= 1) {
        float m2 = __shfl_xor(m, off);
        float d2 = __shfl_xor(den, off);
        float M = fmaxf(m, m2);
        float s1 = __expf(m - M), s2 = __expf(m2 - M);
        den = den * s1 + d2 * s2;
#pragma unroll
        for (int j = 0; j < 10; j++) {
            float n2 = __shfl_xor(num[j], off);
            num[j] = num[j] * s1 + n2 * s2;
        }
        m = M;
    }
    float inv = 1.f / den;
#pragma unroll
    for (int j = 0; j < 10; j++) {
        float v = num[j] * inv + sb[j];
        hout[j] = (v > 0.f) ? v : 0.f;
    }
}

// ---------------- init ----------------
__global__ void k_init(int M) {
    int i = blockIdx.x * blockDim.x + threadIdx.x;
    int tot = NPART * M;
    if (i < tot) ((float*)g_pp)[i] = 0.f;
    if (i < 256) g_bcnt[i] = 0;
    if (i == tot) g_vsum[0] = 0.f;
}

// ---------------- CSR build ----------------
__global__ void k_bhist(const int* __restrict__ dst, int E) {
    __shared__ int hist[256];
    hist[threadIdx.x] = 0;
    __syncthreads();
    for (int e = blockIdx.x * blockDim.x + threadIdx.x; e < E; e += gridDim.x * blockDim.x)
        atomicAdd(&hist[dst[e] >> BKS], 1);
    __syncthreads();
    int v = hist[threadIdx.x];
    if (v) atomicAdd(&g_bcnt[threadIdx.x], v);
}
__global__ void k_bscan() {
    __shared__ int s[256];
    int t = threadIdx.x;
    int v = g_bcnt[t];
    s[t] = v;
    __syncthreads();
    for (int d = 1; d < 256; d <<= 1) {
        int x = (t >= d) ? s[t - d] : 0;
        __syncthreads();
        s[t] += x;
        __syncthreads();
    }
    g_boff[t] = s[t] - v;
    g_bcur[t] = s[t] - v;
}
__global__ void k_bscatter(const int* __restrict__ src, const int* __restrict__ dst, int E) {
    __shared__ int hist[256], cur[256];
    int lo = blockIdx.x * CHUNK;
    int hi = lo + CHUNK; if (hi > E) hi = E;
    int tid = threadIdx.x;
    hist[tid] = 0;
    __syncthreads();
    for (int e = lo + tid; e < hi; e += 256) atomicAdd(&hist[dst[e] >> BKS], 1);
    __syncthreads();
    int h = hist[tid];
    cur[tid] = h ? atomicAdd(&g_bcur[tid], h) : 0;
    __syncthreads();
    for (int e = lo + tid; e < hi; e += 256) {
        int d = dst[e];
        int pos = atomicAdd(&cur[d >> BKS], 1);
        g_staged[pos] = ((unsigned)src[e] << BKS) | (unsigned)(d & ((1 << BKS) - 1));
    }
}
__global__ void k_bgroup(int N, int E, int nbk) {
    __shared__ int cnt[1024], offl[1024], ssum[512];
    int b = blockIdx.x;
    int nodebase = b << BKS;
    int bstart = g_boff[b];
    int bend = (b + 1 < nbk) ? g_boff[b + 1] : E;
    int tid = threadIdx.x;
    cnt[tid] = 0; cnt[tid + 512] = 0;
    __syncthreads();
    for (int e = bstart + tid; e < bend; e += 512)
        atomicAdd(&cnt[g_staged[e] & 1023u], 1);
    __syncthreads();
    int s0 = cnt[2 * tid], s1 = cnt[2 * tid + 1];
    int tsum = s0 + s1;
    ssum[tid] = tsum;
    __syncthreads();
    for (int d = 1; d < 512; d <<= 1) {
        int x = (tid >= d) ? ssum[tid - d] : 0;
        __syncthreads();
        ssum[tid] += x;
        __syncthreads();
    }
    int base = ssum[tid] - tsum;
    offl[2 * tid] = base;
    offl[2 * tid + 1] = base + s0;
    __syncthreads();
    int n0 = nodebase + 2 * tid, n1 = n0 + 1;
    if (n0 < N) { g_off[n0] = bstart + offl[2 * tid]; g_cnt[n0] = s0; }
    if (n1 < N) { g_off[n1] = bstart + offl[2 * tid + 1]; g_cnt[n1] = s1; }
    cnt[2 * tid] = offl[2 * tid];
    cnt[2 * tid + 1] = offl[2 * tid + 1];
    __syncthreads();
    for (int e = bstart + tid; e < bend; e += 512) {
        unsigned w = g_staged[e];
        int p = atomicAdd(&cnt[w & 1023u], 1);
        g_csrc[bstart + p] = (int)(w >> BKS);
    }
}

// ---- layer-1 pre ----
__global__ void k_pre1(const float* __restrict__ x1,
                       const float* __restrict__ wl, const float* __restrict__ wr, int N) {
    __shared__ float swl[150], swr[150];
    for (int t = threadIdx.x; t < 150; t += blockDim.x) { swl[t] = wl[t]; swr[t] = wr[t]; }
    __syncthreads();
    int n = blockIdx.x * blockDim.x + threadIdx.x;
    if (n >= N) return;
    float aL[10], aR[10];
#pragma unroll
    for (int j = 0; j < 10; j++) { aL[j] = 0.f; aR[j] = 0.f; }
    for (int k = 0; k < 15; k++) {
        float v = x1[(size_t)n * 15 + k];
#pragma unroll
        for (int j = 0; j < 10; j++) { aL[j] += v * swl[k * 10 + j]; aR[j] += v * swr[k * 10 + j]; }
    }
    store_xlb(&g_xlbA[(size_t)n * XLU], aL);
#pragma unroll
    for (int j = 0; j < 10; j++) g_xrA[(size_t)n * HS + j] = aR[j];
}

// ---- fused gather(L) + pre(L+1) ----
__global__ void k_gather_pre(const float* __restrict__ x1,
                             const float* __restrict__ att, const float* __restrict__ b,
                             const float* __restrict__ wl, const float* __restrict__ wr,
                             int sel_in, int N) {
    __shared__ float satt[10], sb[10], swl[250], swr[250];
    if (threadIdx.x < 10) { satt[threadIdx.x] = att[threadIdx.x]; sb[threadIdx.x] = b[threadIdx.x]; }
    for (int t = threadIdx.x; t < 250; t += blockDim.x) { swl[t] = wl[t]; swr[t] = wr[t]; }
    __syncthreads();
    int t = blockIdx.x * blockDim.x + threadIdx.x;
    int n = t >> 2, sub = t & 3;
    if (n >= N) return;
    const unsigned* xlb = xlb_buf(sel_in);
    const float* xr_arr = xr_buf(sel_in);
    unsigned* xlb_o = xlb_buf(1 - sel_in);
    float* xr_o = xr_buf(1 - sel_in);
    float h[10];
    gather_core(n, sub, xlb, xr_arr, satt, sb, h);
    if (sub == 0) {
        float aL[10], aR[10];
#pragma unroll
        for (int j = 0; j < 10; j++) { aL[j] = 0.f; aR[j] = 0.f; }
        for (int k = 0; k < 10; k++) {
            float v = h[k];
#pragma unroll
            for (int j = 0; j < 10; j++) { aL[j] += v * swl[k * 10 + j]; aR[j] += v * swr[k * 10 + j]; }
        }
        for (int k = 0; k < 15; k++) {
            float v = x1[(size_t)n * 15 + k];
#pragma unroll
            for (int j = 0; j < 10; j++) { aL[j] += v * swl[(10 + k) * 10 + j]; aR[j] += v * swr[(10 + k) * 10 + j]; }
        }
        store_xlb(&xlb_o[(size_t)n * XLU], aL);
#pragma unroll
        for (int j = 0; j < 10; j++) xr_o[(size_t)n * HS + j] = aR[j];
    }
}

// ---- fused final gather + u-row projections + value head (divergence-free j-stripes) ----
// After gather all 4 sublanes hold identical h. Each sublane computes the j-stripe
// j = sub + 4t of us/ud/ut (5 each) and of the value head (<=4 of 15), staged via LDS.
__global__ void k_gather3_prep(const float* __restrict__ x1,
                               const float* __restrict__ att, const float* __restrict__ b,
                               const float* __restrict__ aw, const float* __restrict__ cw,
                               const float* __restrict__ x2,
                               const float* __restrict__ w1, const float* __restrict__ b1,
                               const float* __restrict__ w2, const float* __restrict__ bias2,
                               int sel_in, int N) {
    __shared__ float satt[10], sb[10];
    __shared__ float sA[48 * 20], sC[23 * 20], sw1[29 * 15];
    __shared__ float sb1[15], sw2v[15], sx2[4], sb2v;
    __shared__ float stgs[64 * 20], stgd[64 * 20], stgt[64 * 20];
    __shared__ float red[256];
    if (threadIdx.x < 10) { satt[threadIdx.x] = att[threadIdx.x]; sb[threadIdx.x] = b[threadIdx.x]; }
    for (int t = threadIdx.x; t < 48 * 20; t += blockDim.x) sA[t] = aw[t];
    for (int t = threadIdx.x; t < 23 * 20; t += blockDim.x) sC[t] = cw[t];
    for (int t = threadIdx.x; t < 29 * 15; t += blockDim.x) sw1[t] = w1[t];
    if (threadIdx.x < 15) { sb1[threadIdx.x] = b1[threadIdx.x]; sw2v[threadIdx.x] = w2[threadIdx.x]; }
    if (threadIdx.x < 4) sx2[threadIdx.x] = x2[threadIdx.x];
    if (threadIdx.x == 0) sb2v = bias2[0];
    __syncthreads();
    int t = blockIdx.x * blockDim.x + threadIdx.x;
    int n = t >> 2, sub = t & 3;
    int ln = threadIdx.x >> 2;      // local node index 0..63
    bool active = (n < N);
    float vout = 0.f;
    if (active) {
        float h[10];
        gather_core(n, sub, xlb_buf(sel_in), xr_buf(sel_in), satt, sb, h);
        float xv[15];
#pragma unroll
        for (int k = 0; k < 15; k++) xv[k] = x1[(size_t)n * 15 + k];
        float t34 = -0.7f * (xv[3] + xv[4]);
        // j-stripes of us/ud/ut (uniform across sublanes)
#pragma unroll
        for (int tt = 0; tt < 5; tt++) {
            int j = sub + 4 * tt;
            float us = 0.f, ud = 0.f, ut = 0.f;
            for (int k = 0; k < 10; k++) {
                float hv = h[k];
                us += hv * sA[k * 20 + j];
                ud += hv * sA[(10 + k) * 20 + j];
                ut += hv * sC[k * 20 + j];
            }
            for (int k = 0; k < 12; k++) {
                float v = xv[3 + k];
                us += v * sA[(20 + k) * 20 + j];
                ut += v * sC[(10 + k) * 20 + j];
            }
            for (int k = 0; k < 14; k++) ud += xv[1 + k] * sA[(32 + k) * 20 + j];
            ud += t34 * sA[47 * 20 + j];
            stgs[ln * 20 + j] = us;
            stgd[ln * 20 + j] = ud;
            stgt[ln * 20 + j] = ut;
        }
        // value-head j-stripe (bias once via sub0)
        vout = (sub == 0) ? sb2v : 0.f;
#pragma unroll
        for (int tt = 0; tt < 4; tt++) {
            int j = sub + 4 * tt;
            if (j < 15) {
                float acc = sb1[j];
                for (int k = 0; k < 10; k++) acc += h[k] * sw1[k * 15 + j];
                for (int k = 0; k < 15; k++) acc += xv[k] * sw1[(10 + k) * 15 + j];
                for (int k = 0; k < 4; k++) acc += sx2[k] * sw1[(25 + k) * 15 + j];
                vout += ((acc > 0.f) ? acc : 0.f) * sw2v[j];
            }
        }
    }
    __syncthreads();
    if (active) {
        if (sub == 0) store_row20_bf(&g_us[(size_t)n * USU], &stgs[ln * 20]);
        else if (sub == 1) store_row20_bf(&g_ud[(size_t)n * USU], &stgd[ln * 20]);
        else if (sub == 2) store_row20_bf(&g_ut[(size_t)n * USU], &stgt[ln * 20]);
    }
    red[threadIdx.x] = vout;
    __syncthreads();
    for (int s = 128; s > 0; s >>= 1) {
        if (threadIdx.x < (unsigned)s) red[threadIdx.x] += red[threadIdx.x + s];
        __syncthreads();
    }
    if (threadIdx.x == 0) atomicAdd(&g_vsum[0], red[0]);
}

// ---- fused attack + deploy scoring; per-partition p histograms ----
__global__ void k_score(const int* __restrict__ asrc, const int* __restrict__ adst,
                        const float* __restrict__ aarm, const int* __restrict__ amove,
                        const float* __restrict__ aw, const float* __restrict__ ab,
                        const float* __restrict__ bw, const float* __restrict__ bb,
                        const int* __restrict__ dtar, const float* __restrict__ darm,
                        const int* __restrict__ dmove,
                        const float* __restrict__ cw, const float* __restrict__ cb,
                        const float* __restrict__ dw, const float* __restrict__ db,
                        int Ma, int Md, int na) {
    __shared__ float swa[20], sbias[20], sw2[20], sb2;
    bool isA = (blockIdx.x < (unsigned)na);
    float* pp = g_pp[blockIdx.x & (NPART - 1)];
    if (threadIdx.x < 20) {
        if (isA) {
            swa[threadIdx.x] = aw[46 * 20 + threadIdx.x] + 0.6f * aw[47 * 20 + threadIdx.x];
            sbias[threadIdx.x] = ab[threadIdx.x];
            sw2[threadIdx.x] = bw[threadIdx.x];
        } else {
            swa[threadIdx.x] = cw[22 * 20 + threadIdx.x];
            sbias[threadIdx.x] = cb[threadIdx.x];
            sw2[threadIdx.x] = dw[threadIdx.x];
        }
    }
    if (threadIdx.x == 0) sb2 = isA ? bb[0] : db[0];
    __syncthreads();
    if (isA) {
        int base = blockIdx.x * 512 + threadIdx.x;
#pragma unroll
        for (int r = 0; r < 2; r++) {
            int i = base + r * 256;
            if (i >= Ma) break;
            int s = asrc[i], d = adst[i];
            float a = aarm[i];
            float us[20], ud[20];
            load_row20_bf(&g_us[(size_t)s * USU], us);
            load_row20_bf(&g_ud[(size_t)d * USU], ud);
            float sres = sb2;
#pragma unroll
            for (int j = 0; j < 20; j++) {
                float acc = sbias[j] + us[j] + ud[j] + a * swa[j];
                float rr = (acc > 0.f) ? acc : 0.f;
                sres += rr * sw2[j];
            }
            atomicAdd(&pp[amove[i]], sres);
        }
    } else {
        int base = (blockIdx.x - na) * 512 + threadIdx.x;
#pragma unroll
        for (int r = 0; r < 2; r++) {
            int i = base + r * 256;
            if (i >= Md) break;
            int t = dtar[i];
            float a = darm[i];
            float ut[20];
            load_row20_bf(&g_ut[(size_t)t * USU], ut);
            float sres = sb2;
#pragma unroll
            for (int j = 0; j < 20; j++) {
                float acc = sbias[j] + ut[j] + a * swa[j];
                float rr = (acc > 0.f) ? acc : 0.f;
                sres += rr * sw2[j];
            }
            atomicAdd(&pp[dmove[i]], sres);
        }
    }
}

// -------- finalize: sum partials -> p; out[0]=V, out[1..M]=log_softmax(p) --------
__global__ void k_final(float* __restrict__ out, int M, int N) {
    __shared__ float red[1024];
    int tid = threadIdx.x;
    float mx = -1e30f;
    for (int i = tid; i < M; i += 1024) {
        float s = 0.f;
#pragma unroll
        for (int q = 0; q < NPART; q++) s += g_pp[q][i];
        g_p[i] = s;
        mx = fmaxf(mx, s);
    }
    red[tid] = mx;
    __syncthreads();
    for (int s = 512; s > 0; s >>= 1) {
        if (tid < s) red[tid] = fmaxf(red[tid], red[tid + s]);
        __syncthreads();
    }
    float pmax = red[0];
    __syncthreads();
    float sm = 0.f;
    for (int i = tid; i < M; i += 1024) sm += __expf(g_p[i] - pmax);
    red[tid] = sm;
    __syncthreads();
    for (int s = 512; s > 0; s >>= 1) {
        if (tid < s) red[tid] += red[tid + s];
        __syncthreads();
    }
    float lse = pmax + logf(red[0]);
    if (tid == 0) out[0] = tanhf(g_vsum[0] / (float)N);
    for (int i = tid; i < M; i += 1024) out[1 + i] = g_p[i] - lse;
}

extern "C" void kernel_launch(void* const* d_in, const int* in_sizes, int n_in,
                              void* d_out, int out_size, void* d_ws, size_t ws_size,
                              hipStream_t stream) {
    const float* x1 = (const float*)d_in[0];
    const float* x2 = (const float*)d_in[1];
    const int* edges = (const int*)d_in[2];
    const int* asrc = (const int*)d_in[3];
    const int* adst = (const int*)d_in[4];
    const float* aarm = (const float*)d_in[5];
    const int* amove = (const int*)d_in[6];
    const int* dtar = (const int*)d_in[7];
    const float* darm = (const float*)d_in[8];
    const int* dmove = (const int*)d_in[9];
    const int pb = n_in - 24;
    const float* g1_wl  = (const float*)d_in[pb + 0];
    const float* g1_wr  = (const float*)d_in[pb + 1];
    const float* g1_att = (const float*)d_in[pb + 2];
    const float* g1_b   = (const float*)d_in[pb + 3];
    const float* g2_wl  = (const float*)d_in[pb + 4];
    const float* g2_wr  = (const float*)d_in[pb + 5];
    const float* g2_att = (const float*)d_in[pb + 6];
    const float* g2_b   = (const float*)d_in[pb + 7];
    const float* g3_wl  = (const float*)d_in[pb + 8];
    const float* g3_wr  = (const float*)d_in[pb + 9];
    const float* g3_att = (const float*)d_in[pb + 10];
    const float* g3_b   = (const float*)d_in[pb + 11];
    const float* lin_w  = (const float*)d_in[pb + 12];
    const float* lin_b  = (const float*)d_in[pb + 13];
    const float* lin2_w = (const float*)d_in[pb + 14];
    const float* lin2_b = (const float*)d_in[pb + 15];
    const float* aaa_w  = (const float*)d_in[pb + 16];
    const float* aaa_b  = (const float*)d_in[pb + 17];
    const float* bbb_w  = (const float*)d_in[pb + 18];
    const float* bbb_b  = (const float*)d_in[pb + 19];
    const float* ccc_w  = (const float*)d_in[pb + 20];
    const float* ccc_b  = (const float*)d_in[pb + 21];
    const float* ddd_w  = (const float*)d_in[pb + 22];
    const float* ddd_b  = (const float*)d_in[pb + 23];

    int N = in_sizes[0] / 15;
    int E = in_sizes[2] / 2;
    const int Ma = in_sizes[3];
    const int Md = in_sizes[7];
    int M = out_size - 1;
    if (N > N_CAP) N = N_CAP;
    if (E > E_CAP) E = E_CAP;
    if (M > M_CAP) M = M_CAP;
    const int* src = edges;
    const int* dst = edges + E;

    const int nb = (N + 255) / 256;
    const int nb4 = (4 * N + 255) / 256;
    const int nbk = (N + (1 << BKS) - 1) >> BKS;
    const int nsc = (E + CHUNK - 1) / CHUNK;
    const int na = (Ma + 511) / 512, nd = (Md + 511) / 512;

    // init + CSR build
    k_init<<<(NPART * M + 256) / 256, 256, 0, stream>>>(M);
    k_bhist<<<512, 256, 0, stream>>>(dst, E);
    k_bscan<<<1, 256, 0, stream>>>();
    k_bscatter<<<nsc, 256, 0, stream>>>(src, dst, E);
    k_bgroup<<<nbk, 512, 0, stream>>>(N, E, nbk);

    // GAT layers (layer 3 fused with u-row projections + value head)
    k_pre1<<<nb, 256, 0, stream>>>(x1, g1_wl, g1_wr, N);
    k_gather_pre<<<nb4, 256, 0, stream>>>(x1, g1_att, g1_b, g2_wl, g2_wr, 0, N);
    k_gather_pre<<<nb4, 256, 0, stream>>>(x1, g2_att, g2_b, g3_wl, g3_wr, 1, N);
    k_gather3_prep<<<nb4, 256, 0, stream>>>(x1, g3_att, g3_b, aaa_w, ccc_w, x2,
                                            lin_w, lin_b, lin2_w, lin2_b, 0, N);

    // scoring + finalize
    k_score<<<na + nd, 256, 0, stream>>>(asrc, adst, aarm, amove, aaa_w, aaa_b, bbb_w, bbb_b,
                                         dtar, darm, dmove, ccc_w, ccc_b, ddd_w, ddd_b,
                                         Ma, Md, na);
    k_final<<<1, 1024, 0, stream>>>((float*)d_out, M, N);
}

// Round 21
// 608.958 us; speedup vs baseline: 1.1293x; 1.1293x over previous
//
#include <hip/hip_runtime.h>
#include <hip/hip_bf16.h>

#define HS 12       // stride for h / xr rows (48B)
#define XLU 8       // stride (uints) for bf16 xl rows (32B, sector-aligned)
#define USU 12      // stride (uints) for packed bf16 u-rows (48B)
#define N_CAP 200000
#define M_CAP 32768
#define E_CAP 3200000
#define BKS 10      // 1024 nodes per bucket (196 buckets)
#define CHUNK 6144  // edges per k_bscatter block

// Static device scratch
__device__ __align__(32) unsigned g_xlbA[(size_t)N_CAP * XLU];
__device__ __align__(32) unsigned g_xlbB[(size_t)N_CAP * XLU];
__device__ __align__(16) float    g_xrA[(size_t)N_CAP * HS];
__device__ __align__(16) float    g_xrB[(size_t)N_CAP * HS];
__device__ __align__(16) float    g_h [(size_t)N_CAP * HS];
__device__ __align__(16) unsigned g_us[(size_t)N_CAP * USU];
__device__ __align__(16) unsigned g_ud[(size_t)N_CAP * USU];
__device__ __align__(16) unsigned g_ut[(size_t)N_CAP * USU];
__device__ int      g_cnt[N_CAP];
__device__ int      g_off[N_CAP];
__device__ int      g_bcnt[256];
__device__ int      g_boff[256];
__device__ int      g_bcur[256];
__device__ unsigned g_staged[E_CAP];
__device__ int      g_csrc[E_CAP];
__device__ float    g_p[M_CAP];
__device__ float    g_vsum[1];

__device__ __forceinline__ unsigned* xlb_buf(int s) { return s ? g_xlbB : g_xlbA; }
__device__ __forceinline__ float*    xr_buf(int s)  { return s ? g_xrB : g_xrA; }

__device__ __forceinline__ void load_row10(const float* row, float* v) {
    const float4* r4 = (const float4*)row;
    float4 a = r4[0], b = r4[1];
    float2 c = ((const float2*)row)[4];
    v[0] = a.x; v[1] = a.y; v[2] = a.z; v[3] = a.w;
    v[4] = b.x; v[5] = b.y; v[6] = b.z; v[7] = b.w;
    v[8] = c.x; v[9] = c.y;
}
__device__ __forceinline__ unsigned pack_bf2(float a, float b) {
    unsigned ua = __float_as_uint(a); ua = (ua + 0x7fffu + ((ua >> 16) & 1u)) >> 16;
    unsigned ub = __float_as_uint(b); ub = (ub + 0x7fffu + ((ub >> 16) & 1u)) >> 16;
    return ua | (ub << 16);
}
__device__ __forceinline__ void unpack_bf2(unsigned u, float& a, float& b) {
    a = __uint_as_float(u << 16);
    b = __uint_as_float(u & 0xffff0000u);
}
__device__ __forceinline__ void load_xlb(const unsigned* row, float* v) {
    uint4 q = ((const uint4*)row)[0];
    unsigned q4 = row[4];
    unpack_bf2(q.x, v[0], v[1]); unpack_bf2(q.y, v[2], v[3]);
    unpack_bf2(q.z, v[4], v[5]); unpack_bf2(q.w, v[6], v[7]);
    unpack_bf2(q4, v[8], v[9]);
}
__device__ __forceinline__ void store_xlb(unsigned* row, const float* v) {
    ((uint4*)row)[0] = make_uint4(pack_bf2(v[0], v[1]), pack_bf2(v[2], v[3]),
                                  pack_bf2(v[4], v[5]), pack_bf2(v[6], v[7]));
    row[4] = pack_bf2(v[8], v[9]);
}
__device__ __forceinline__ void load_row20_bf(const unsigned* row, float* v) {
    const uint4* r4 = (const uint4*)row;
    uint4 q0 = r4[0], q1 = r4[1], q2 = r4[2];
    unpack_bf2(q0.x, v[0], v[1]);   unpack_bf2(q0.y, v[2], v[3]);
    unpack_bf2(q0.z, v[4], v[5]);   unpack_bf2(q0.w, v[6], v[7]);
    unpack_bf2(q1.x, v[8], v[9]);   unpack_bf2(q1.y, v[10], v[11]);
    unpack_bf2(q1.z, v[12], v[13]); unpack_bf2(q1.w, v[14], v[15]);
    unpack_bf2(q2.x, v[16], v[17]); unpack_bf2(q2.y, v[18], v[19]);
}
__device__ __forceinline__ void store_row20_bf(unsigned* row, const float* v) {
    uint4* r4 = (uint4*)row;
    r4[0] = make_uint4(pack_bf2(v[0], v[1]), pack_bf2(v[2], v[3]),
                       pack_bf2(v[4], v[5]), pack_bf2(v[6], v[7]));
    r4[1] = make_uint4(pack_bf2(v[8], v[9]), pack_bf2(v[10], v[11]),
                       pack_bf2(v[12], v[13]), pack_bf2(v[14], v[15]));
    r4[2] = make_uint4(pack_bf2(v[16], v[17]), pack_bf2(v[18], v[19]), 0u, 0u);
}

// ---- shared gather core: returns h[10] for node n in lane (sub==0) registers ----
__device__ __forceinline__ void gather_core(int n, int sub, const unsigned* xlb,
                                            const float* xr_arr, const float* satt,
                                            const float* sb, float* hout) {
    float xr[10];
    load_row10(&xr_arr[(size_t)n * HS], xr);
    float m = -1e30f, den = 0.f, num[10];
#pragma unroll
    for (int j = 0; j < 10; j++) num[j] = 0.f;
    if (sub == 0) {   // self-loop
        float xls[10];
        load_xlb(&xlb[(size_t)n * XLU], xls);
        float acc = 0.f;
#pragma unroll
        for (int k = 0; k < 10; k++) {
            float v = xls[k] + xr[k];
            v = (v > 0.f) ? v : 0.2f * v;
            acc += v * satt[k];
            num[k] = xls[k];
        }
        m = acc;
        den = 1.f;
    }
    int lo = g_off[n], hi = lo + g_cnt[n];
    for (int e = lo + sub; e < hi; e += 4) {
        int s = g_csrc[e];
        float xls[10];
        load_xlb(&xlb[(size_t)s * XLU], xls);
        float acc = 0.f;
#pragma unroll
        for (int k = 0; k < 10; k++) {
            float v = xls[k] + xr[k];
            v = (v > 0.f) ? v : 0.2f * v;
            acc += v * satt[k];
        }
        if (acc > m) {
            float sc = __expf(m - acc);
            den *= sc;
#pragma unroll
            for (int j = 0; j < 10; j++) num[j] *= sc;
            m = acc;
        }
        float w = __expf(acc - m);
        den += w;
#pragma unroll
        for (int j = 0; j < 10; j++) num[j] += w * xls[j];
    }
#pragma unroll
    for (int off = 1; off <= 2; off <<= 1) {
        float m2 = __shfl_xor(m, off);
        float d2 = __shfl_xor(den, off);
        float M = fmaxf(m, m2);
        float s1 = __expf(m - M), s2 = __expf(m2 - M);
        den = den * s1 + d2 * s2;
#pragma unroll
        for (int j = 0; j < 10; j++) {
            float n2 = __shfl_xor(num[j], off);
            num[j] = num[j] * s1 + n2 * s2;
        }
        m = M;
    }
    float inv = 1.f / den;
#pragma unroll
    for (int j = 0; j < 10; j++) {
        float v = num[j] * inv + sb[j];
        hout[j] = (v > 0.f) ? v : 0.f;
    }
}

// ---------------- init ----------------
__global__ void k_init(int M) {
    int i = blockIdx.x * blockDim.x + threadIdx.x;
    if (i < M) g_p[i] = 0.f;
    if (i < 256) g_bcnt[i] = 0;
    if (i == M) g_vsum[0] = 0.f;
}

// ---------------- CSR build ----------------
__global__ void k_bhist(const int* __restrict__ dst, int E) {
    __shared__ int hist[256];
    hist[threadIdx.x] = 0;
    __syncthreads();
    for (int e = blockIdx.x * blockDim.x + threadIdx.x; e < E; e += gridDim.x * blockDim.x)
        atomicAdd(&hist[dst[e] >> BKS], 1);
    __syncthreads();
    int v = hist[threadIdx.x];
    if (v) atomicAdd(&g_bcnt[threadIdx.x], v);
}
__global__ void k_bscan() {
    __shared__ int s[256];
    int t = threadIdx.x;
    int v = g_bcnt[t];
    s[t] = v;
    __syncthreads();
    for (int d = 1; d < 256; d <<= 1) {
        int x = (t >= d) ? s[t - d] : 0;
        __syncthreads();
        s[t] += x;
        __syncthreads();
    }
    g_boff[t] = s[t] - v;
    g_bcur[t] = s[t] - v;
}
__global__ void k_bscatter(const int* __restrict__ src, const int* __restrict__ dst, int E) {
    __shared__ int hist[256], cur[256];
    int lo = blockIdx.x * CHUNK;
    int hi = lo + CHUNK; if (hi > E) hi = E;
    int tid = threadIdx.x;
    hist[tid] = 0;
    __syncthreads();
    for (int e = lo + tid; e < hi; e += 256) atomicAdd(&hist[dst[e] >> BKS], 1);
    __syncthreads();
    int h = hist[tid];
    cur[tid] = h ? atomicAdd(&g_bcur[tid], h) : 0;
    __syncthreads();
    for (int e = lo + tid; e < hi; e += 256) {
        int d = dst[e];
        int pos = atomicAdd(&cur[d >> BKS], 1);
        g_staged[pos] = ((unsigned)src[e] << BKS) | (unsigned)(d & ((1 << BKS) - 1));
    }
}
__global__ void k_bgroup(int N, int E, int nbk) {
    __shared__ int cnt[1024], offl[1024], ssum[512];
    int b = blockIdx.x;
    int nodebase = b << BKS;
    int bstart = g_boff[b];
    int bend = (b + 1 < nbk) ? g_boff[b + 1] : E;
    int tid = threadIdx.x;
    cnt[tid] = 0; cnt[tid + 512] = 0;
    __syncthreads();
    for (int e = bstart + tid; e < bend; e += 512)
        atomicAdd(&cnt[g_staged[e] & 1023u], 1);
    __syncthreads();
    int s0 = cnt[2 * tid], s1 = cnt[2 * tid + 1];
    int tsum = s0 + s1;
    ssum[tid] = tsum;
    __syncthreads();
    for (int d = 1; d < 512; d <<= 1) {
        int x = (tid >= d) ? ssum[tid - d] : 0;
        __syncthreads();
        ssum[tid] += x;
        __syncthreads();
    }
    int base = ssum[tid] - tsum;
    offl[2 * tid] = base;
    offl[2 * tid + 1] = base + s0;
    __syncthreads();
    int n0 = nodebase + 2 * tid, n1 = n0 + 1;
    if (n0 < N) { g_off[n0] = bstart + offl[2 * tid]; g_cnt[n0] = s0; }
    if (n1 < N) { g_off[n1] = bstart + offl[2 * tid + 1]; g_cnt[n1] = s1; }
    cnt[2 * tid] = offl[2 * tid];
    cnt[2 * tid + 1] = offl[2 * tid + 1];
    __syncthreads();
    for (int e = bstart + tid; e < bend; e += 512) {
        unsigned w = g_staged[e];
        int p = atomicAdd(&cnt[w & 1023u], 1);
        g_csrc[bstart + p] = (int)(w >> BKS);
    }
}

// ---- layer-1 pre ----
__global__ void k_pre1(const float* __restrict__ x1,
                       const float* __restrict__ wl, const float* __restrict__ wr, int N) {
    __shared__ float swl[150], swr[150];
    for (int t = threadIdx.x; t < 150; t += blockDim.x) { swl[t] = wl[t]; swr[t] = wr[t]; }
    __syncthreads();
    int n = blockIdx.x * blockDim.x + threadIdx.x;
    if (n >= N) return;
    float aL[10], aR[10];
#pragma unroll
    for (int j = 0; j < 10; j++) { aL[j] = 0.f; aR[j] = 0.f; }
    for (int k = 0; k < 15; k++) {
        float v = x1[(size_t)n * 15 + k];
#pragma unroll
        for (int j = 0; j < 10; j++) { aL[j] += v * swl[k * 10 + j]; aR[j] += v * swr[k * 10 + j]; }
    }
    store_xlb(&g_xlbA[(size_t)n * XLU], aL);
#pragma unroll
    for (int j = 0; j < 10; j++) g_xrA[(size_t)n * HS + j] = aR[j];
}

// ---- fused gather(L) + pre(L+1) ----
__global__ void k_gather_pre(const float* __restrict__ x1,
                             const float* __restrict__ att, const float* __restrict__ b,
                             const float* __restrict__ wl, const float* __restrict__ wr,
                             int sel_in, int N) {
    __shared__ float satt[10], sb[10], swl[250], swr[250];
    if (threadIdx.x < 10) { satt[threadIdx.x] = att[threadIdx.x]; sb[threadIdx.x] = b[threadIdx.x]; }
    for (int t = threadIdx.x; t < 250; t += blockDim.x) { swl[t] = wl[t]; swr[t] = wr[t]; }
    __syncthreads();
    int t = blockIdx.x * blockDim.x + threadIdx.x;
    int n = t >> 2, sub = t & 3;
    if (n >= N) return;
    const unsigned* xlb = xlb_buf(sel_in);
    const float* xr_arr = xr_buf(sel_in);
    unsigned* xlb_o = xlb_buf(1 - sel_in);
    float* xr_o = xr_buf(1 - sel_in);
    float h[10];
    gather_core(n, sub, xlb, xr_arr, satt, sb, h);
    if (sub == 0) {
        float aL[10], aR[10];
#pragma unroll
        for (int j = 0; j < 10; j++) { aL[j] = 0.f; aR[j] = 0.f; }
        for (int k = 0; k < 10; k++) {
            float v = h[k];
#pragma unroll
            for (int j = 0; j < 10; j++) { aL[j] += v * swl[k * 10 + j]; aR[j] += v * swr[k * 10 + j]; }
        }
        for (int k = 0; k < 15; k++) {
            float v = x1[(size_t)n * 15 + k];
#pragma unroll
            for (int j = 0; j < 10; j++) { aL[j] += v * swl[(10 + k) * 10 + j]; aR[j] += v * swr[(10 + k) * 10 + j]; }
        }
        store_xlb(&xlb_o[(size_t)n * XLU], aL);
#pragma unroll
        for (int j = 0; j < 10; j++) xr_o[(size_t)n * HS + j] = aR[j];
    }
}

// ---- final gather (layer 3): writes h ----
__global__ void k_gather3(const float* __restrict__ att, const float* __restrict__ b,
                          int sel_in, int N) {
    __shared__ float satt[10], sb[10];
    if (threadIdx.x < 10) { satt[threadIdx.x] = att[threadIdx.x]; sb[threadIdx.x] = b[threadIdx.x]; }
    __syncthreads();
    int t = blockIdx.x * blockDim.x + threadIdx.x;
    int n = t >> 2, sub = t & 3;
    if (n >= N) return;
    float h[10];
    gather_core(n, sub, xlb_buf(sel_in), xr_buf(sel_in), satt, sb, h);
    if (sub == 0) {
#pragma unroll
        for (int j = 0; j < 10; j++) g_h[(size_t)n * HS + j] = h[j];
    }
}

// ---- fused: pre-project u-rows (bf16) + value head partial sum ----
__global__ void k_prep_value(const float* __restrict__ x1,
                             const float* __restrict__ aw, const float* __restrict__ cw,
                             const float* __restrict__ x2,
                             const float* __restrict__ w1, const float* __restrict__ b1,
                             const float* __restrict__ w2, const float* __restrict__ bias2,
                             int N) {
    __shared__ float sA[48 * 20], sC[23 * 20], sw1[29 * 15];
    __shared__ float sb1[15], sw2v[15], sx2[4], sb2v;
    __shared__ float red[256];
    for (int t = threadIdx.x; t < 48 * 20; t += blockDim.x) sA[t] = aw[t];
    for (int t = threadIdx.x; t < 23 * 20; t += blockDim.x) sC[t] = cw[t];
    for (int t = threadIdx.x; t < 29 * 15; t += blockDim.x) sw1[t] = w1[t];
    if (threadIdx.x < 15) { sb1[threadIdx.x] = b1[threadIdx.x]; sw2v[threadIdx.x] = w2[threadIdx.x]; }
    if (threadIdx.x < 4) sx2[threadIdx.x] = x2[threadIdx.x];
    if (threadIdx.x == 0) sb2v = bias2[0];
    __syncthreads();
    int n = blockIdx.x * blockDim.x + threadIdx.x;
    float vout = 0.f;
    if (n < N) {
        float hv[10], xv[15];
        load_row10(&g_h[(size_t)n * HS], hv);
#pragma unroll
        for (int k = 0; k < 15; k++) xv[k] = x1[(size_t)n * 15 + k];
        float us[20], ud[20], ut[20];
#pragma unroll
        for (int j = 0; j < 20; j++) { us[j] = 0.f; ud[j] = 0.f; ut[j] = 0.f; }
        for (int k = 0; k < 10; k++) {
            float h = hv[k];
#pragma unroll
            for (int j = 0; j < 20; j++) {
                us[j] += h * sA[k * 20 + j];
                ud[j] += h * sA[(10 + k) * 20 + j];
                ut[j] += h * sC[k * 20 + j];
            }
        }
        for (int k = 0; k < 12; k++) {
            float v = xv[3 + k];
#pragma unroll
            for (int j = 0; j < 20; j++) {
                us[j] += v * sA[(20 + k) * 20 + j];
                ut[j] += v * sC[(10 + k) * 20 + j];
            }
        }
        for (int k = 0; k < 14; k++) {
            float v = xv[1 + k];
#pragma unroll
            for (int j = 0; j < 20; j++) ud[j] += v * sA[(32 + k) * 20 + j];
        }
        float t34 = -0.7f * (xv[3] + xv[4]);
#pragma unroll
        for (int j = 0; j < 20; j++) ud[j] += t34 * sA[47 * 20 + j];
        store_row20_bf(&g_us[(size_t)n * USU], us);
        store_row20_bf(&g_ud[(size_t)n * USU], ud);
        store_row20_bf(&g_ut[(size_t)n * USU], ut);
        float acc[15];
#pragma unroll
        for (int j = 0; j < 15; j++) acc[j] = sb1[j];
        for (int k = 0; k < 10; k++) {
            float f = hv[k];
#pragma unroll
            for (int j = 0; j < 15; j++) acc[j] += f * sw1[k * 15 + j];
        }
        for (int k = 0; k < 15; k++) {
            float f = xv[k];
#pragma unroll
            for (int j = 0; j < 15; j++) acc[j] += f * sw1[(10 + k) * 15 + j];
        }
        for (int k = 0; k < 4; k++) {
            float f = sx2[k];
#pragma unroll
            for (int j = 0; j < 15; j++) acc[j] += f * sw1[(25 + k) * 15 + j];
        }
        vout = sb2v;
#pragma unroll
        for (int j = 0; j < 15; j++) { float r = (acc[j] > 0.f) ? acc[j] : 0.f; vout += r * sw2v[j]; }
    }
    red[threadIdx.x] = vout;
    __syncthreads();
    for (int s = 128; s > 0; s >>= 1) {
        if (threadIdx.x < (unsigned)s) red[threadIdx.x] += red[threadIdx.x + s];
        __syncthreads();
    }
    if (threadIdx.x == 0) atomicAdd(&g_vsum[0], red[0]);
}

// ---- fused attack + deploy scoring (block-range split) ----
__global__ void k_score(const int* __restrict__ asrc, const int* __restrict__ adst,
                        const float* __restrict__ aarm, const int* __restrict__ amove,
                        const float* __restrict__ aw, const float* __restrict__ ab,
                        const float* __restrict__ bw, const float* __restrict__ bb,
                        const int* __restrict__ dtar, const float* __restrict__ darm,
                        const int* __restrict__ dmove,
                        const float* __restrict__ cw, const float* __restrict__ cb,
                        const float* __restrict__ dw, const float* __restrict__ db,
                        int Ma, int Md, int na) {
    __shared__ float swa[20], sbias[20], sw2[20], sb2;
    bool isA = (blockIdx.x < (unsigned)na);
    if (threadIdx.x < 20) {
        if (isA) {
            swa[threadIdx.x] = aw[46 * 20 + threadIdx.x] + 0.6f * aw[47 * 20 + threadIdx.x];
            sbias[threadIdx.x] = ab[threadIdx.x];
            sw2[threadIdx.x] = bw[threadIdx.x];
        } else {
            swa[threadIdx.x] = cw[22 * 20 + threadIdx.x];
            sbias[threadIdx.x] = cb[threadIdx.x];
            sw2[threadIdx.x] = dw[threadIdx.x];
        }
    }
    if (threadIdx.x == 0) sb2 = isA ? bb[0] : db[0];
    __syncthreads();
    if (isA) {
        int i = blockIdx.x * blockDim.x + threadIdx.x;
        if (i >= Ma) return;
        int s = asrc[i], d = adst[i];
        float a = aarm[i];
        float us[20], ud[20];
        load_row20_bf(&g_us[(size_t)s * USU], us);
        load_row20_bf(&g_ud[(size_t)d * USU], ud);
        float sres = sb2;
#pragma unroll
        for (int j = 0; j < 20; j++) {
            float acc = sbias[j] + us[j] + ud[j] + a * swa[j];
            float r = (acc > 0.f) ? acc : 0.f;
            sres += r * sw2[j];
        }
        atomicAdd(&g_p[amove[i]], sres);
    } else {
        int i = (blockIdx.x - na) * blockDim.x + threadIdx.x;
        if (i >= Md) return;
        int t = dtar[i];
        float a = darm[i];
        float ut[20];
        load_row20_bf(&g_ut[(size_t)t * USU], ut);
        float sres = sb2;
#pragma unroll
        for (int j = 0; j < 20; j++) {
            float acc = sbias[j] + ut[j] + a * swa[j];
            float r = (acc > 0.f) ? acc : 0.f;
            sres += r * sw2[j];
        }
        atomicAdd(&g_p[dmove[i]], sres);
    }
}

// -------- finalize (f32 output): out[0]=V, out[1..M]=log_softmax(p) --------
__global__ void k_final(float* __restrict__ out, int M, int N) {
    __shared__ float red[1024];
    int tid = threadIdx.x;
    float mx = -1e30f;
    for (int i = tid; i < M; i += 1024) mx = fmaxf(mx, g_p[i]);
    red[tid] = mx;
    __syncthreads();
    for (int s = 512; s > 0; s >>= 1) {
        if (tid < s) red[tid] = fmaxf(red[tid], red[tid + s]);
        __syncthreads();
    }
    float pmax = red[0];
    __syncthreads();
    float sm = 0.f;
    for (int i = tid; i < M; i += 1024) sm += __expf(g_p[i] - pmax);
    red[tid] = sm;
    __syncthreads();
    for (int s = 512; s > 0; s >>= 1) {
        if (tid < s) red[tid] += red[tid + s];
        __syncthreads();
    }
    float lse = pmax + logf(red[0]);
    if (tid == 0) out[0] = tanhf(g_vsum[0] / (float)N);
    for (int i = tid; i < M; i += 1024) out[1 + i] = g_p[i] - lse;
}

extern "C" void kernel_launch(void* const* d_in, const int* in_sizes, int n_in,
                              void* d_out, int out_size, void* d_ws, size_t ws_size,
                              hipStream_t stream) {
    const float* x1 = (const float*)d_in[0];
    const float* x2 = (const float*)d_in[1];
    const int* edges = (const int*)d_in[2];
    const int* asrc = (const int*)d_in[3];
    const int* adst = (const int*)d_in[4];
    const float* aarm = (const float*)d_in[5];
    const int* amove = (const int*)d_in[6];
    const int* dtar = (const int*)d_in[7];
    const float* darm = (const float*)d_in[8];
    const int* dmove = (const int*)d_in[9];
    const int pb = n_in - 24;
    const float* g1_wl  = (const float*)d_in[pb + 0];
    const float* g1_wr  = (const float*)d_in[pb + 1];
    const float* g1_att = (const float*)d_in[pb + 2];
    const float* g1_b   = (const float*)d_in[pb + 3];
    const float* g2_wl  = (const float*)d_in[pb + 4];
    const float* g2_wr  = (const float*)d_in[pb + 5];
    const float* g2_att = (const float*)d_in[pb + 6];
    const float* g2_b   = (const float*)d_in[pb + 7];
    const float* g3_wl  = (const float*)d_in[pb + 8];
    const float* g3_wr  = (const float*)d_in[pb + 9];
    const float* g3_att = (const float*)d_in[pb + 10];
    const float* g3_b   = (const float*)d_in[pb + 11];
    const float* lin_w  = (const float*)d_in[pb + 12];
    const float* lin_b  = (const float*)d_in[pb + 13];
    const float* lin2_w = (const float*)d_in[pb + 14];
    const float* lin2_b = (const float*)d_in[pb + 15];
    const float* aaa_w  = (const float*)d_in[pb + 16];
    const float* aaa_b  = (const float*)d_in[pb + 17];
    const float* bbb_w  = (const float*)d_in[pb + 18];
    const float* bbb_b  = (const float*)d_in[pb + 19];
    const float* ccc_w  = (const float*)d_in[pb + 20];
    const float* ccc_b  = (const float*)d_in[pb + 21];
    const float* ddd_w  = (const float*)d_in[pb + 22];
    const float* ddd_b  = (const float*)d_in[pb + 23];

    int N = in_sizes[0] / 15;
    int E = in_sizes[2] / 2;
    const int Ma = in_sizes[3];
    const int Md = in_sizes[7];
    int M = out_size - 1;
    if (N > N_CAP) N = N_CAP;
    if (E > E_CAP) E = E_CAP;
    if (M > M_CAP) M = M_CAP;
    const int* src = edges;
    const int* dst = edges + E;

    const int nb = (N + 255) / 256;
    const int nb4 = (4 * N + 255) / 256;
    const int nbk = (N + (1 << BKS) - 1) >> BKS;
    const int nsc = (E + CHUNK - 1) / CHUNK;
    const int na = (Ma + 255) / 256, nd = (Md + 255) / 256;

    // init + CSR build (once; reused by all 3 layers)
    k_init<<<(M + 256) / 256, 256, 0, stream>>>(M);
    k_bhist<<<512, 256, 0, stream>>>(dst, E);
    k_bscan<<<1, 256, 0, stream>>>();
    k_bscatter<<<nsc, 256, 0, stream>>>(src, dst, E);
    k_bgroup<<<nbk, 512, 0, stream>>>(N, E, nbk);

    // GAT layers: pre1 -> A; gather1+pre2 -> B; gather2+pre3 -> A; gather3 -> h
    k_pre1<<<nb, 256, 0, stream>>>(x1, g1_wl, g1_wr, N);
    k_gather_pre<<<nb4, 256, 0, stream>>>(x1, g1_att, g1_b, g2_wl, g2_wr, 0, N);
    k_gather_pre<<<nb4, 256, 0, stream>>>(x1, g2_att, g2_b, g3_wl, g3_wr, 1, N);
    k_gather3<<<nb4, 256, 0, stream>>>(g3_att, g3_b, 0, N);

    // u-row projection + value head, fused attack+deploy scoring, finalize
    k_prep_value<<<nb, 256, 0, stream>>>(x1, aaa_w, ccc_w, x2, lin_w, lin_b, lin2_w, lin2_b, N);
    k_score<<<na + nd, 256, 0, stream>>>(asrc, adst, aarm, amove, aaa_w, aaa_b, bbb_w, bbb_b,
                                         dtar, darm, dmove, ccc_w, ccc_b, ddd_w, ddd_b,
                                         Ma, Md, na);
    k_final<<<1, 1024, 0, stream>>>((float*)d_out, M, N);
}

// Round 22
// 582.007 us; speedup vs baseline: 1.1816x; 1.0463x over previous
//
#include <hip/hip_runtime.h>
#include <hip/hip_bf16.h>

#define HS 12       // stride for h / xr rows (48B)
#define XLU 8       // stride (uints) for bf16 xl rows (32B, sector-aligned)
#define USU 12      // stride (uints) for packed bf16 u-rows (48B)
#define NPART 8     // p-histogram partitions
#define N_CAP 200000
#define M_CAP 32768
#define E_CAP 3200000
#define BKS 10      // 1024 nodes per bucket (196 buckets)
#define CHUNK 6144  // edges per k_bscatter block

// Static device scratch
__device__ __align__(32) unsigned g_xlbA[(size_t)N_CAP * XLU];
__device__ __align__(32) unsigned g_xlbB[(size_t)N_CAP * XLU];
__device__ __align__(16) float    g_xrA[(size_t)N_CAP * HS];
__device__ __align__(16) float    g_xrB[(size_t)N_CAP * HS];
__device__ __align__(16) float    g_h [(size_t)N_CAP * HS];
__device__ __align__(16) unsigned g_us[(size_t)N_CAP * USU];
__device__ __align__(16) unsigned g_ud[(size_t)N_CAP * USU];
__device__ __align__(16) unsigned g_ut[(size_t)N_CAP * USU];
__device__ int      g_cnt[N_CAP];
__device__ int      g_off[N_CAP];
__device__ int      g_bcnt[256];
__device__ int      g_boff[256];
__device__ int      g_bcur[256];
__device__ unsigned g_staged[E_CAP];
__device__ int      g_csrc[E_CAP];
__device__ __align__(64) float g_pp[NPART][M_CAP];
__device__ float    g_p[M_CAP];
__device__ float    g_vsum[1];

__device__ __forceinline__ unsigned* xlb_buf(int s) { return s ? g_xlbB : g_xlbA; }
__device__ __forceinline__ float*    xr_buf(int s)  { return s ? g_xrB : g_xrA; }

__device__ __forceinline__ void load_row10(const float* row, float* v) {
    const float4* r4 = (const float4*)row;
    float4 a = r4[0], b = r4[1];
    float2 c = ((const float2*)row)[4];
    v[0] = a.x; v[1] = a.y; v[2] = a.z; v[3] = a.w;
    v[4] = b.x; v[5] = b.y; v[6] = b.z; v[7] = b.w;
    v[8] = c.x; v[9] = c.y;
}
__device__ __forceinline__ unsigned pack_bf2(float a, float b) {
    unsigned ua = __float_as_uint(a); ua = (ua + 0x7fffu + ((ua >> 16) & 1u)) >> 16;
    unsigned ub = __float_as_uint(b); ub = (ub + 0x7fffu + ((ub >> 16) & 1u)) >> 16;
    return ua | (ub << 16);
}
__device__ __forceinline__ void unpack_bf2(unsigned u, float& a, float& b) {
    a = __uint_as_float(u << 16);
    b = __uint_as_float(u & 0xffff0000u);
}
__device__ __forceinline__ void load_xlb(const unsigned* row, float* v) {
    uint4 q = ((const uint4*)row)[0];
    unsigned q4 = row[4];
    unpack_bf2(q.x, v[0], v[1]); unpack_bf2(q.y, v[2], v[3]);
    unpack_bf2(q.z, v[4], v[5]); unpack_bf2(q.w, v[6], v[7]);
    unpack_bf2(q4, v[8], v[9]);
}
__device__ __forceinline__ void store_xlb(unsigned* row, const float* v) {
    ((uint4*)row)[0] = make_uint4(pack_bf2(v[0], v[1]), pack_bf2(v[2], v[3]),
                                  pack_bf2(v[4], v[5]), pack_bf2(v[6], v[7]));
    row[4] = pack_bf2(v[8], v[9]);
}
__device__ __forceinline__ void load_row20_bf(const unsigned* row, float* v) {
    const uint4* r4 = (const uint4*)row;
    uint4 q0 = r4[0], q1 = r4[1], q2 = r4[2];
    unpack_bf2(q0.x, v[0], v[1]);   unpack_bf2(q0.y, v[2], v[3]);
    unpack_bf2(q0.z, v[4], v[5]);   unpack_bf2(q0.w, v[6], v[7]);
    unpack_bf2(q1.x, v[8], v[9]);   unpack_bf2(q1.y, v[10], v[11]);
    unpack_bf2(q1.z, v[12], v[13]); unpack_bf2(q1.w, v[14], v[15]);
    unpack_bf2(q2.x, v[16], v[17]); unpack_bf2(q2.y, v[18], v[19]);
}
__device__ __forceinline__ void store_row20_bf(unsigned* row, const float* v) {
    uint4* r4 = (uint4*)row;
    r4[0] = make_uint4(pack_bf2(v[0], v[1]), pack_bf2(v[2], v[3]),
                       pack_bf2(v[4], v[5]), pack_bf2(v[6], v[7]));
    r4[1] = make_uint4(pack_bf2(v[8], v[9]), pack_bf2(v[10], v[11]),
                       pack_bf2(v[12], v[13]), pack_bf2(v[14], v[15]));
    r4[2] = make_uint4(pack_bf2(v[16], v[17]), pack_bf2(v[18], v[19]), 0u, 0u);
}

// ---- shared gather core ----
__device__ __forceinline__ void gather_core(int n, int sub, const unsigned* xlb,
                                            const float* xr_arr, const float* satt,
                                            const float* sb, float* hout) {
    float xr[10];
    load_row10(&xr_arr[(size_t)n * HS], xr);
    float m = -1e30f, den = 0.f, num[10];
#pragma unroll
    for (int j = 0; j < 10; j++) num[j] = 0.f;
    if (sub == 0) {   // self-loop
        float xls[10];
        load_xlb(&xlb[(size_t)n * XLU], xls);
        float acc = 0.f;
#pragma unroll
        for (int k = 0; k < 10; k++) {
            float v = xls[k] + xr[k];
            v = (v > 0.f) ? v : 0.2f * v;
            acc += v * satt[k];
            num[k] = xls[k];
        }
        m = acc;
        den = 1.f;
    }
    int lo = g_off[n], hi = lo + g_cnt[n];
    for (int e = lo + sub; e < hi; e += 4) {
        int s = g_csrc[e];
        float xls[10];
        load_xlb(&xlb[(size_t)s * XLU], xls);
        float acc = 0.f;
#pragma unroll
        for (int k = 0; k < 10; k++) {
            float v = xls[k] + xr[k];
            v = (v > 0.f) ? v : 0.2f * v;
            acc += v * satt[k];
        }
        if (acc > m) {
            float sc = __expf(m - acc);
            den *= sc;
#pragma unroll
            for (int j = 0; j < 10; j++) num[j] *= sc;
            m = acc;
        }
        float w = __expf(acc - m);
        den += w;
#pragma unroll
        for (int j = 0; j < 10; j++) num[j] += w * xls[j];
    }
#pragma unroll
    for (int off = 1; off <= 2; off <<= 1) {
        float m2 = __shfl_xor(m, off);
        float d2 = __shfl_xor(den, off);
        float M = fmaxf(m, m2);
        float s1 = __expf(m - M), s2 = __expf(m2 - M);
        den = den * s1 + d2 * s2;
#pragma unroll
        for (int j = 0; j < 10; j++) {
            float n2 = __shfl_xor(num[j], off);
            num[j] = num[j] * s1 + n2 * s2;
        }
        m = M;
    }
    float inv = 1.f / den;
#pragma unroll
    for (int j = 0; j < 10; j++) {
        float v = num[j] * inv + sb[j];
        hout[j] = (v > 0.f) ? v : 0.f;
    }
}

// ---------------- init ----------------
__global__ void k_init(int M) {
    int i = blockIdx.x * blockDim.x + threadIdx.x;
    int tot = NPART * M;
    if (i < tot) ((float*)g_pp)[i] = 0.f;
    if (i < 256) g_bcnt[i] = 0;
    if (i == tot) g_vsum[0] = 0.f;
}

// ---------------- CSR build ----------------
__global__ void k_bhist(const int* __restrict__ dst, int E) {
    __shared__ int hist[256];
    hist[threadIdx.x] = 0;
    __syncthreads();
    for (int e = blockIdx.x * blockDim.x + threadIdx.x; e < E; e += gridDim.x * blockDim.x)
        atomicAdd(&hist[dst[e] >> BKS], 1);
    __syncthreads();
    int v = hist[threadIdx.x];
    if (v) atomicAdd(&g_bcnt[threadIdx.x], v);
}
__global__ void k_bscan() {
    __shared__ int s[256];
    int t = threadIdx.x;
    int v = g_bcnt[t];
    s[t] = v;
    __syncthreads();
    for (int d = 1; d < 256; d <<= 1) {
        int x = (t >= d) ? s[t - d] : 0;
        __syncthreads();
        s[t] += x;
        __syncthreads();
    }
    g_boff[t] = s[t] - v;
    g_bcur[t] = s[t] - v;
}
__global__ void k_bscatter(const int* __restrict__ src, const int* __restrict__ dst, int E) {
    __shared__ int hist[256], cur[256];
    int lo = blockIdx.x * CHUNK;
    int hi = lo + CHUNK; if (hi > E) hi = E;
    int tid = threadIdx.x;
    hist[tid] = 0;
    __syncthreads();
    for (int e = lo + tid; e < hi; e += 256) atomicAdd(&hist[dst[e] >> BKS], 1);
    __syncthreads();
    int h = hist[tid];
    cur[tid] = h ? atomicAdd(&g_bcur[tid], h) : 0;
    __syncthreads();
    for (int e = lo + tid; e < hi; e += 256) {
        int d = dst[e];
        int pos = atomicAdd(&cur[d >> BKS], 1);
        g_staged[pos] = ((unsigned)src[e] << BKS) | (unsigned)(d & ((1 << BKS) - 1));
    }
}
__global__ void k_bgroup(int N, int E, int nbk) {
    __shared__ int cnt[1024], offl[1024], ssum[512];
    int b = blockIdx.x;
    int nodebase = b << BKS;
    int bstart = g_boff[b];
    int bend = (b + 1 < nbk) ? g_boff[b + 1] : E;
    int tid = threadIdx.x;
    cnt[tid] = 0; cnt[tid + 512] = 0;
    __syncthreads();
    for (int e = bstart + tid; e < bend; e += 512)
        atomicAdd(&cnt[g_staged[e] & 1023u], 1);
    __syncthreads();
    int s0 = cnt[2 * tid], s1 = cnt[2 * tid + 1];
    int tsum = s0 + s1;
    ssum[tid] = tsum;
    __syncthreads();
    for (int d = 1; d < 512; d <<= 1) {
        int x = (tid >= d) ? ssum[tid - d] : 0;
        __syncthreads();
        ssum[tid] += x;
        __syncthreads();
    }
    int base = ssum[tid] - tsum;
    offl[2 * tid] = base;
    offl[2 * tid + 1] = base + s0;
    __syncthreads();
    int n0 = nodebase + 2 * tid, n1 = n0 + 1;
    if (n0 < N) { g_off[n0] = bstart + offl[2 * tid]; g_cnt[n0] = s0; }
    if (n1 < N) { g_off[n1] = bstart + offl[2 * tid + 1]; g_cnt[n1] = s1; }
    cnt[2 * tid] = offl[2 * tid];
    cnt[2 * tid + 1] = offl[2 * tid + 1];
    __syncthreads();
    for (int e = bstart + tid; e < bend; e += 512) {
        unsigned w = g_staged[e];
        int p = atomicAdd(&cnt[w & 1023u], 1);
        g_csrc[bstart + p] = (int)(w >> BKS);
    }
}

// ---- layer-1 pre ----
__global__ void k_pre1(const float* __restrict__ x1,
                       const float* __restrict__ wl, const float* __restrict__ wr, int N) {
    __shared__ float swl[150], swr[150];
    for (int t = threadIdx.x; t < 150; t += blockDim.x) { swl[t] = wl[t]; swr[t] = wr[t]; }
    __syncthreads();
    int n = blockIdx.x * blockDim.x + threadIdx.x;
    if (n >= N) return;
    float aL[10], aR[10];
#pragma unroll
    for (int j = 0; j < 10; j++) { aL[j] = 0.f; aR[j] = 0.f; }
    for (int k = 0; k < 15; k++) {
        float v = x1[(size_t)n * 15 + k];
#pragma unroll
        for (int j = 0; j < 10; j++) { aL[j] += v * swl[k * 10 + j]; aR[j] += v * swr[k * 10 + j]; }
    }
    store_xlb(&g_xlbA[(size_t)n * XLU], aL);
#pragma unroll
    for (int j = 0; j < 10; j++) g_xrA[(size_t)n * HS + j] = aR[j];
}

// ---- fused gather(L) + pre(L+1) ----
__global__ void k_gather_pre(const float* __restrict__ x1,
                             const float* __restrict__ att, const float* __restrict__ b,
                             const float* __restrict__ wl, const float* __restrict__ wr,
                             int sel_in, int N) {
    __shared__ float satt[10], sb[10], swl[250], swr[250];
    if (threadIdx.x < 10) { satt[threadIdx.x] = att[threadIdx.x]; sb[threadIdx.x] = b[threadIdx.x]; }
    for (int t = threadIdx.x; t < 250; t += blockDim.x) { swl[t] = wl[t]; swr[t] = wr[t]; }
    __syncthreads();
    int t = blockIdx.x * blockDim.x + threadIdx.x;
    int n = t >> 2, sub = t & 3;
    if (n >= N) return;
    const unsigned* xlb = xlb_buf(sel_in);
    const float* xr_arr = xr_buf(sel_in);
    unsigned* xlb_o = xlb_buf(1 - sel_in);
    float* xr_o = xr_buf(1 - sel_in);
    float h[10];
    gather_core(n, sub, xlb, xr_arr, satt, sb, h);
    if (sub == 0) {
        float aL[10], aR[10];
#pragma unroll
        for (int j = 0; j < 10; j++) { aL[j] = 0.f; aR[j] = 0.f; }
        for (int k = 0; k < 10; k++) {
            float v = h[k];
#pragma unroll
            for (int j = 0; j < 10; j++) { aL[j] += v * swl[k * 10 + j]; aR[j] += v * swr[k * 10 + j]; }
        }
        for (int k = 0; k < 15; k++) {
            float v = x1[(size_t)n * 15 + k];
#pragma unroll
            for (int j = 0; j < 10; j++) { aL[j] += v * swl[(10 + k) * 10 + j]; aR[j] += v * swr[(10 + k) * 10 + j]; }
        }
        store_xlb(&xlb_o[(size_t)n * XLU], aL);
#pragma unroll
        for (int j = 0; j < 10; j++) xr_o[(size_t)n * HS + j] = aR[j];
    }
}

// ---- final gather (layer 3): writes h ----
__global__ void k_gather3(const float* __restrict__ att, const float* __restrict__ b,
                          int sel_in, int N) {
    __shared__ float satt[10], sb[10];
    if (threadIdx.x < 10) { satt[threadIdx.x] = att[threadIdx.x]; sb[threadIdx.x] = b[threadIdx.x]; }
    __syncthreads();
    int t = blockIdx.x * blockDim.x + threadIdx.x;
    int n = t >> 2, sub = t & 3;
    if (n >= N) return;
    float h[10];
    gather_core(n, sub, xlb_buf(sel_in), xr_buf(sel_in), satt, sb, h);
    if (sub == 0) {
#pragma unroll
        for (int j = 0; j < 10; j++) g_h[(size_t)n * HS + j] = h[j];
    }
}

// ---- fused: pre-project u-rows (bf16) + value head partial sum ----
// __launch_bounds__(256,1): ~110 live floats/thread -> needs >=128 VGPRs.
// Default cap (64 VGPR) caused scratch spilling: WRITE_SIZE 155MB vs 29MB payload.
__global__ void __launch_bounds__(256, 1)
k_prep_value(const float* __restrict__ x1,
             const float* __restrict__ aw, const float* __restrict__ cw,
             const float* __restrict__ x2,
             const float* __restrict__ w1, const float* __restrict__ b1,
             const float* __restrict__ w2, const float* __restrict__ bias2,
             int N) {
    __shared__ float sA[48 * 20], sC[23 * 20], sw1[29 * 15];
    __shared__ float sb1[15], sw2v[15], sx2[4], sb2v;
    __shared__ float red[256];
    for (int t = threadIdx.x; t < 48 * 20; t += blockDim.x) sA[t] = aw[t];
    for (int t = threadIdx.x; t < 23 * 20; t += blockDim.x) sC[t] = cw[t];
    for (int t = threadIdx.x; t < 29 * 15; t += blockDim.x) sw1[t] = w1[t];
    if (threadIdx.x < 15) { sb1[threadIdx.x] = b1[threadIdx.x]; sw2v[threadIdx.x] = w2[threadIdx.x]; }
    if (threadIdx.x < 4) sx2[threadIdx.x] = x2[threadIdx.x];
    if (threadIdx.x == 0) sb2v = bias2[0];
    __syncthreads();
    int n = blockIdx.x * blockDim.x + threadIdx.x;
    float vout = 0.f;
    if (n < N) {
        float hv[10], xv[15];
        load_row10(&g_h[(size_t)n * HS], hv);
#pragma unroll
        for (int k = 0; k < 15; k++) xv[k] = x1[(size_t)n * 15 + k];
        float us[20], ud[20], ut[20];
#pragma unroll
        for (int j = 0; j < 20; j++) { us[j] = 0.f; ud[j] = 0.f; ut[j] = 0.f; }
        for (int k = 0; k < 10; k++) {
            float h = hv[k];
#pragma unroll
            for (int j = 0; j < 20; j++) {
                us[j] += h * sA[k * 20 + j];
                ud[j] += h * sA[(10 + k) * 20 + j];
                ut[j] += h * sC[k * 20 + j];
            }
        }
        for (int k = 0; k < 12; k++) {
            float v = xv[3 + k];
#pragma unroll
            for (int j = 0; j < 20; j++) {
                us[j] += v * sA[(20 + k) * 20 + j];
                ut[j] += v * sC[(10 + k) * 20 + j];
            }
        }
        for (int k = 0; k < 14; k++) {
            float v = xv[1 + k];
#pragma unroll
            for (int j = 0; j < 20; j++) ud[j] += v * sA[(32 + k) * 20 + j];
        }
        float t34 = -0.7f * (xv[3] + xv[4]);
#pragma unroll
        for (int j = 0; j < 20; j++) ud[j] += t34 * sA[47 * 20 + j];
        store_row20_bf(&g_us[(size_t)n * USU], us);
        store_row20_bf(&g_ud[(size_t)n * USU], ud);
        store_row20_bf(&g_ut[(size_t)n * USU], ut);
        float acc[15];
#pragma unroll
        for (int j = 0; j < 15; j++) acc[j] = sb1[j];
        for (int k = 0; k < 10; k++) {
            float f = hv[k];
#pragma unroll
            for (int j = 0; j < 15; j++) acc[j] += f * sw1[k * 15 + j];
        }
        for (int k = 0; k < 15; k++) {
            float f = xv[k];
#pragma unroll
            for (int j = 0; j < 15; j++) acc[j] += f * sw1[(10 + k) * 15 + j];
        }
        for (int k = 0; k < 4; k++) {
            float f = sx2[k];
#pragma unroll
            for (int j = 0; j < 15; j++) acc[j] += f * sw1[(25 + k) * 15 + j];
        }
        vout = sb2v;
#pragma unroll
        for (int j = 0; j < 15; j++) { float r = (acc[j] > 0.f) ? acc[j] : 0.f; vout += r * sw2v[j]; }
    }
    red[threadIdx.x] = vout;
    __syncthreads();
    for (int s = 128; s > 0; s >>= 1) {
        if (threadIdx.x < (unsigned)s) red[threadIdx.x] += red[threadIdx.x + s];
        __syncthreads();
    }
    if (threadIdx.x == 0) atomicAdd(&g_vsum[0], red[0]);
}

// ---- fused attack + deploy scoring; atomics into per-partition p histograms ----
__global__ void k_score(const int* __restrict__ asrc, const int* __restrict__ adst,
                        const float* __restrict__ aarm, const int* __restrict__ amove,
                        const float* __restrict__ aw, const float* __restrict__ ab,
                        const float* __restrict__ bw, const float* __restrict__ bb,
                        const int* __restrict__ dtar, const float* __restrict__ darm,
                        const int* __restrict__ dmove,
                        const float* __restrict__ cw, const float* __restrict__ cb,
                        const float* __restrict__ dw, const float* __restrict__ db,
                        int Ma, int Md, int na) {
    __shared__ float swa[20], sbias[20], sw2[20], sb2;
    bool isA = (blockIdx.x < (unsigned)na);
    float* pp = g_pp[blockIdx.x & (NPART - 1)];
    if (threadIdx.x < 20) {
        if (isA) {
            swa[threadIdx.x] = aw[46 * 20 + threadIdx.x] + 0.6f * aw[47 * 20 + threadIdx.x];
            sbias[threadIdx.x] = ab[threadIdx.x];
            sw2[threadIdx.x] = bw[threadIdx.x];
        } else {
            swa[threadIdx.x] = cw[22 * 20 + threadIdx.x];
            sbias[threadIdx.x] = cb[threadIdx.x];
            sw2[threadIdx.x] = dw[threadIdx.x];
        }
    }
    if (threadIdx.x == 0) sb2 = isA ? bb[0] : db[0];
    __syncthreads();
    if (isA) {
        int i = blockIdx.x * blockDim.x + threadIdx.x;
        if (i >= Ma) return;
        int s = asrc[i], d = adst[i];
        float a = aarm[i];
        float us[20], ud[20];
        load_row20_bf(&g_us[(size_t)s * USU], us);
        load_row20_bf(&g_ud[(size_t)d * USU], ud);
        float sres = sb2;
#pragma unroll
        for (int j = 0; j < 20; j++) {
            float acc = sbias[j] + us[j] + ud[j] + a * swa[j];
            float r = (acc > 0.f) ? acc : 0.f;
            sres += r * sw2[j];
        }
        atomicAdd(&pp[amove[i]], sres);
    } else {
        int i = (blockIdx.x - na) * blockDim.x + threadIdx.x;
        if (i >= Md) return;
        int t = dtar[i];
        float a = darm[i];
        float ut[20];
        load_row20_bf(&g_ut[(size_t)t * USU], ut);
        float sres = sb2;
#pragma unroll
        for (int j = 0; j < 20; j++) {
            float acc = sbias[j] + ut[j] + a * swa[j];
            float r = (acc > 0.f) ? acc : 0.f;
            sres += r * sw2[j];
        }
        atomicAdd(&pp[dmove[i]], sres);
    }
}

// -------- finalize: sum partials; out[0]=V, out[1..M]=log_softmax(p) --------
__global__ void k_final(float* __restrict__ out, int M, int N) {
    __shared__ float red[1024];
    int tid = threadIdx.x;
    float mx = -1e30f;
    for (int i = tid; i < M; i += 1024) {
        float s = 0.f;
#pragma unroll
        for (int q = 0; q < NPART; q++) s += g_pp[q][i];
        g_p[i] = s;
        mx = fmaxf(mx, s);
    }
    red[tid] = mx;
    __syncthreads();
    for (int s = 512; s > 0; s >>= 1) {
        if (tid < s) red[tid] = fmaxf(red[tid], red[tid + s]);
        __syncthreads();
    }
    float pmax = red[0];
    __syncthreads();
    float sm = 0.f;
    for (int i = tid; i < M; i += 1024) sm += __expf(g_p[i] - pmax);
    red[tid] = sm;
    __syncthreads();
    for (int s = 512; s > 0; s >>= 1) {
        if (tid < s) red[tid] += red[tid + s];
        __syncthreads();
    }
    float lse = pmax + logf(red[0]);
    if (tid == 0) out[0] = tanhf(g_vsum[0] / (float)N);
    for (int i = tid; i < M; i += 1024) out[1 + i] = g_p[i] - lse;
}

extern "C" void kernel_launch(void* const* d_in, const int* in_sizes, int n_in,
                              void* d_out, int out_size, void* d_ws, size_t ws_size,
                              hipStream_t stream) {
    const float* x1 = (const float*)d_in[0];
    const float* x2 = (const float*)d_in[1];
    const int* edges = (const int*)d_in[2];
    const int* asrc = (const int*)d_in[3];
    const int* adst = (const int*)d_in[4];
    const float* aarm = (const float*)d_in[5];
    const int* amove = (const int*)d_in[6];
    const int* dtar = (const int*)d_in[7];
    const float* darm = (const float*)d_in[8];
    const int* dmove = (const int*)d_in[9];
    const int pb = n_in - 24;
    const float* g1_wl  = (const float*)d_in[pb + 0];
    const float* g1_wr  = (const float*)d_in[pb + 1];
    const float* g1_att = (const float*)d_in[pb + 2];
    const float* g1_b   = (const float*)d_in[pb + 3];
    const float* g2_wl  = (const float*)d_in[pb + 4];
    const float* g2_wr  = (const float*)d_in[pb + 5];
    const float* g2_att = (const float*)d_in[pb + 6];
    const float* g2_b   = (const float*)d_in[pb + 7];
    const float* g3_wl  = (const float*)d_in[pb + 8];
    const float* g3_wr  = (const float*)d_in[pb + 9];
    const float* g3_att = (const float*)d_in[pb + 10];
    const float* g3_b   = (const float*)d_in[pb + 11];
    const float* lin_w  = (const float*)d_in[pb + 12];
    const float* lin_b  = (const float*)d_in[pb + 13];
    const float* lin2_w = (const float*)d_in[pb + 14];
    const float* lin2_b = (const float*)d_in[pb + 15];
    const float* aaa_w  = (const float*)d_in[pb + 16];
    const float* aaa_b  = (const float*)d_in[pb + 17];
    const float* bbb_w  = (const float*)d_in[pb + 18];
    const float* bbb_b  = (const float*)d_in[pb + 19];
    const float* ccc_w  = (const float*)d_in[pb + 20];
    const float* ccc_b  = (const float*)d_in[pb + 21];
    const float* ddd_w  = (const float*)d_in[pb + 22];
    const float* ddd_b  = (const float*)d_in[pb + 23];

    int N = in_sizes[0] / 15;
    int E = in_sizes[2] / 2;
    const int Ma = in_sizes[3];
    const int Md = in_sizes[7];
    int M = out_size - 1;
    if (N > N_CAP) N = N_CAP;
    if (E > E_CAP) E = E_CAP;
    if (M > M_CAP) M = M_CAP;
    const int* src = edges;
    const int* dst = edges + E;

    const int nb = (N + 255) / 256;
    const int nb4 = (4 * N + 255) / 256;
    const int nbk = (N + (1 << BKS) - 1) >> BKS;
    const int nsc = (E + CHUNK - 1) / CHUNK;
    const int na = (Ma + 255) / 256, nd = (Md + 255) / 256;

    // init + CSR build (once; reused by all 3 layers)
    k_init<<<(NPART * M + 256) / 256, 256, 0, stream>>>(M);
    k_bhist<<<512, 256, 0, stream>>>(dst, E);
    k_bscan<<<1, 256, 0, stream>>>();
    k_bscatter<<<nsc, 256, 0, stream>>>(src, dst, E);
    k_bgroup<<<nbk, 512, 0, stream>>>(N, E, nbk);

    // GAT layers: pre1 -> A; gather1+pre2 -> B; gather2+pre3 -> A; gather3 -> h
    k_pre1<<<nb, 256, 0, stream>>>(x1, g1_wl, g1_wr, N);
    k_gather_pre<<<nb4, 256, 0, stream>>>(x1, g1_att, g1_b, g2_wl, g2_wr, 0, N);
    k_gather_pre<<<nb4, 256, 0, stream>>>(x1, g2_att, g2_b, g3_wl, g3_wr, 1, N);
    k_gather3<<<nb4, 256, 0, stream>>>(g3_att, g3_b, 0, N);

    // u-row projection + value head, fused attack+deploy scoring, finalize
    k_prep_value<<<nb, 256, 0, stream>>>(x1, aaa_w, ccc_w, x2, lin_w, lin_b, lin2_w, lin2_b, N);
    k_score<<<na + nd, 256, 0, stream>>>(asrc, adst, aarm, amove, aaa_w, aaa_b, bbb_w, bbb_b,
                                         dtar, darm, dmove, ccc_w, ccc_b, ddd_w, ddd_b,
                                         Ma, Md, na);
    k_final<<<1, 1024, 0, stream>>>((float*)d_out, M, N);
}